// Round 2
// baseline (660.022 us; speedup 1.0000x reference)
//
#include <hip/hip_runtime.h>
#include <hip/hip_bf16.h>

#define SEQ 1024
#define DIM 1024
#define NH 16

typedef __bf16 bf16_t;
typedef __bf16 bf16x8 __attribute__((ext_vector_type(8)));
typedef __bf16 bf16x4 __attribute__((ext_vector_type(4)));
typedef float f32x4 __attribute__((ext_vector_type(4)));

__device__ __forceinline__ f32x4 mfma16(bf16x8 a, bf16x8 b, f32x4 c) {
    return __builtin_amdgcn_mfma_f32_16x16x32_bf16(a, b, c, 0, 0, 0);
}

// ---------------- LayerNorm: one block per row of 1024 ----------------
__global__ __launch_bounds__(256) void ln_kernel(const float* __restrict__ in,
                                                 const float* __restrict__ g,
                                                 const float* __restrict__ bsh,
                                                 float* __restrict__ out) {
    __shared__ float red[4], red2[4];
    const int row = blockIdx.x, tid = threadIdx.x;
    const float4 v = ((const float4*)(in + (size_t)row * DIM))[tid];
    float s = v.x + v.y + v.z + v.w;
#pragma unroll
    for (int o = 32; o; o >>= 1) s += __shfl_down(s, o, 64);
    if ((tid & 63) == 0) red[tid >> 6] = s;
    __syncthreads();
    const float mean = (red[0] + red[1] + red[2] + red[3]) * (1.0f / DIM);
    const float dx = v.x - mean, dy = v.y - mean, dz = v.z - mean, dw = v.w - mean;
    float s2 = dx * dx + dy * dy + dz * dz + dw * dw;
#pragma unroll
    for (int o = 32; o; o >>= 1) s2 += __shfl_down(s2, o, 64);
    if ((tid & 63) == 0) red2[tid >> 6] = s2;
    __syncthreads();
    const float var = (red2[0] + red2[1] + red2[2] + red2[3]) * (1.0f / DIM);
    const float rs = rsqrtf(var + 1e-5f);
    const float4 gv = ((const float4*)g)[tid];
    const float4 bv = ((const float4*)bsh)[tid];
    float4 o4;
    o4.x = dx * rs * gv.x + bv.x;
    o4.y = dy * rs * gv.y + bv.y;
    o4.z = dz * rs * gv.z + bv.z;
    o4.w = dw * rs * gv.w + bv.w;
    ((float4*)(out + (size_t)row * DIM))[tid] = o4;
}

// ---------------- RoPE in-place on q,k sections of qkv (bf16) ----------------
__global__ __launch_bounds__(256) void rope_kernel(bf16_t* __restrict__ qkv,
                                                   const float* __restrict__ rp) {
    const int t = blockIdx.x * 256 + threadIdx.x;  // 4096*512 threads
    const int row = t >> 9;
    const int rem = t & 511;
    const int h = rem >> 5, d = rem & 31;
    const int s = row & (SEQ - 1);
    const float p0 = rp[s * 64 + d];
    const float p1 = rp[s * 64 + d + 32];
    float s0, c0, s1, c1;
    sincosf(p0, &s0, &c0);
    sincosf(p1, &s1, &c1);
    const size_t base = (size_t)row * 3072 + h * 64 + d;
#pragma unroll
    for (int off = 0; off <= 1024; off += 1024) {
        const float a = (float)qkv[base + off];
        const float b = (float)qkv[base + off + 32];
        qkv[base + off] = (bf16_t)(a * c0 - b * s0);
        qkv[base + off + 32] = (bf16_t)(b * c1 + a * s1);
    }
}

// ---------------- generic MFMA GEMM: C = epi(A @ W^T + bias) ----------------
// A: M x K (f32 or bf16, row-major, lda); W: N x K (f32, row-major, ldw)
// block = 256 thr (4 waves, 2x2), tile 128x128, K-step 32.
enum { EPI_BF16 = 0, EPI_F32_RESID = 1, EPI_BF16_GELU = 2, EPI_BF16_SIGMUL = 3 };

template <bool A_BF16, int EPI>
__global__ __launch_bounds__(256) void gemm_kernel(
    const void* __restrict__ Av, int lda, const float* __restrict__ W, int ldw,
    const float* __restrict__ bias, const void* __restrict__ aux,
    void* __restrict__ outv, int ldo, int K) {
    __shared__ bf16_t As[128 * 40];
    __shared__ bf16_t Bs[128 * 40];
    const int tid = threadIdx.x;
    const int wave = tid >> 6, lane = tid & 63;
    const int wr = wave >> 1, wc = wave & 1;
    const int lr = lane & 15, hi = lane >> 4;
    const int rowA0 = blockIdx.y * 128, rowB0 = blockIdx.x * 128;

    f32x4 acc[4][4];
#pragma unroll
    for (int m = 0; m < 4; ++m)
#pragma unroll
        for (int n = 0; n < 4; ++n) acc[m][n] = (f32x4){0.f, 0.f, 0.f, 0.f};

    for (int k0 = 0; k0 < K; k0 += 32) {
        if constexpr (A_BF16) {
            const bf16_t* A = (const bf16_t*)Av;
#pragma unroll
            for (int t = 0; t < 2; ++t) {
                const int idx = t * 256 + tid;         // 0..511
                const int r = idx >> 2, c = (idx & 3) * 8;
                bf16x8 av = *(const bf16x8*)(A + (size_t)(rowA0 + r) * lda + k0 + c);
                *(bf16x8*)&As[r * 40 + c] = av;
            }
        } else {
            const float* A = (const float*)Av;
#pragma unroll
            for (int t = 0; t < 4; ++t) {
                const int idx = t * 256 + tid;         // 0..1023
                const int r = idx >> 3, c = (idx & 7) * 4;
                const float4 av = *(const float4*)(A + (size_t)(rowA0 + r) * lda + k0 + c);
                bf16x4 ap = {(bf16_t)av.x, (bf16_t)av.y, (bf16_t)av.z, (bf16_t)av.w};
                *(bf16x4*)&As[r * 40 + c] = ap;
            }
        }
#pragma unroll
        for (int t = 0; t < 4; ++t) {
            const int idx = t * 256 + tid;
            const int r = idx >> 3, c = (idx & 7) * 4;
            const float4 wv = *(const float4*)(W + (size_t)(rowB0 + r) * ldw + k0 + c);
            bf16x4 wp = {(bf16_t)wv.x, (bf16_t)wv.y, (bf16_t)wv.z, (bf16_t)wv.w};
            *(bf16x4*)&Bs[r * 40 + c] = wp;
        }
        __syncthreads();
        bf16x8 af[4], bfr[4];
#pragma unroll
        for (int m = 0; m < 4; ++m)
            af[m] = *(const bf16x8*)&As[(wr * 64 + m * 16 + lr) * 40 + hi * 8];
#pragma unroll
        for (int n = 0; n < 4; ++n)
            bfr[n] = *(const bf16x8*)&Bs[(wc * 64 + n * 16 + lr) * 40 + hi * 8];
#pragma unroll
        for (int m = 0; m < 4; ++m)
#pragma unroll
            for (int n = 0; n < 4; ++n) acc[m][n] = mfma16(af[m], bfr[n], acc[m][n]);
        __syncthreads();
    }

#pragma unroll
    for (int m = 0; m < 4; ++m) {
#pragma unroll
        for (int j = 0; j < 4; ++j) {
            const int row = rowA0 + wr * 64 + m * 16 + hi * 4 + j;
#pragma unroll
            for (int n = 0; n < 4; ++n) {
                const int col = rowB0 + wc * 64 + n * 16 + lr;
                float val = acc[m][n][j] + bias[col];
                const size_t oidx = (size_t)row * ldo + col;
                if constexpr (EPI == EPI_BF16) {
                    ((bf16_t*)outv)[oidx] = (bf16_t)val;
                } else if constexpr (EPI == EPI_F32_RESID) {
                    ((float*)outv)[oidx] = val + ((const float*)aux)[oidx];
                } else if constexpr (EPI == EPI_BF16_GELU) {
                    ((bf16_t*)outv)[oidx] =
                        (bf16_t)(0.5f * val * (1.0f + erff(val * 0.70710678118f)));
                } else {  // EPI_BF16_SIGMUL
                    const float sg = 1.0f / (1.0f + expf(-val));
                    ((bf16_t*)outv)[oidx] =
                        (bf16_t)(sg * (float)((const bf16_t*)aux)[oidx]);
                }
            }
        }
    }
}

// ---------------- flash attention (non-causal), 4 waves, 64 q-rows/block ----
// q/k/v are bf16 buffers with per-row leading dims; head h at column off+h*64.
#define ALD 72
__global__ __launch_bounds__(256) void attn_kernel(
    const bf16_t* __restrict__ qp, int ldq, int qoff,
    const bf16_t* __restrict__ kp, int ldk, int koff,
    const bf16_t* __restrict__ vp, int ldv, int voff, int skv,
    const float* __restrict__ resid, float* __restrict__ outp, float scale) {
    __shared__ bf16_t Ks[64 * ALD];
    __shared__ bf16_t Vt[64 * ALD];
    __shared__ bf16_t Ps[4 * 16 * ALD];
    const int b = blockIdx.z, h = blockIdx.y, qt = blockIdx.x;
    const int tid = threadIdx.x;
    const int wave = tid >> 6, lane = tid & 63;
    const int lr = lane & 15, hi = lane >> 4;

    const size_t qrow = (size_t)(b * SEQ + qt * 64 + wave * 16 + lr);
    const bf16_t* qb = qp + qrow * ldq + qoff + h * 64;
    const bf16x8 qf0 = *(const bf16x8*)(qb + hi * 8);
    const bf16x8 qf1 = *(const bf16x8*)(qb + 32 + hi * 8);

    f32x4 oacc[4];
#pragma unroll
    for (int n = 0; n < 4; ++n) oacc[n] = (f32x4){0.f, 0.f, 0.f, 0.f};
    float mrun[4] = {-1e30f, -1e30f, -1e30f, -1e30f};
    float lrun[4] = {0.f, 0.f, 0.f, 0.f};

    bf16_t* pw = &Ps[wave * 16 * ALD];
    const int nkt = skv >> 6;
    for (int kt = 0; kt < nkt; ++kt) {
#pragma unroll
        for (int t = 0; t < 2; ++t) {
            const int idx = t * 256 + tid;  // 0..511
            const int key = idx >> 3, c8 = (idx & 7) * 8;
            const size_t krow = (size_t)(b * skv + kt * 64 + key);
            bf16x8 kv = *(const bf16x8*)(kp + krow * ldk + koff + h * 64 + c8);
            *(bf16x8*)&Ks[key * ALD + c8] = kv;
            bf16x8 vv = *(const bf16x8*)(vp + krow * ldv + voff + h * 64 + c8);
#pragma unroll
            for (int i = 0; i < 8; ++i) Vt[(c8 + i) * ALD + key] = vv[i];
        }
        __syncthreads();

        f32x4 s[4];
#pragma unroll
        for (int n = 0; n < 4; ++n) {
            f32x4 z = (f32x4){0.f, 0.f, 0.f, 0.f};
            z = mfma16(qf0, *(const bf16x8*)&Ks[(n * 16 + lr) * ALD + hi * 8], z);
            z = mfma16(qf1, *(const bf16x8*)&Ks[(n * 16 + lr) * ALD + 32 + hi * 8], z);
            s[n] = z * scale;
        }
        float alpha[4];
#pragma unroll
        for (int j = 0; j < 4; ++j) {
            float mt = fmaxf(fmaxf(s[0][j], s[1][j]), fmaxf(s[2][j], s[3][j]));
#pragma unroll
            for (int o = 8; o >= 1; o >>= 1) mt = fmaxf(mt, __shfl_xor(mt, o, 64));
            const float mnew = fmaxf(mrun[j], mt);
            alpha[j] = expf(mrun[j] - mnew);
            float rsum = 0.f;
#pragma unroll
            for (int n = 0; n < 4; ++n) {
                const float p = expf(s[n][j] - mnew);
                s[n][j] = p;
                rsum += p;
            }
#pragma unroll
            for (int o = 8; o >= 1; o >>= 1) rsum += __shfl_xor(rsum, o, 64);
            lrun[j] = lrun[j] * alpha[j] + rsum;
            mrun[j] = mnew;
        }
        // write P (bf16) and rescale O
#pragma unroll
        for (int j = 0; j < 4; ++j) {
            const int pr = hi * 4 + j;
#pragma unroll
            for (int n = 0; n < 4; ++n) pw[pr * ALD + n * 16 + lr] = (bf16_t)s[n][j];
        }
#pragma unroll
        for (int n = 0; n < 4; ++n)
#pragma unroll
            for (int j = 0; j < 4; ++j) oacc[n][j] *= alpha[j];
        // PV
#pragma unroll
        for (int ks = 0; ks < 2; ++ks) {
            const bf16x8 pa = *(const bf16x8*)&pw[lr * ALD + ks * 32 + hi * 8];
#pragma unroll
            for (int n = 0; n < 4; ++n) {
                const bf16x8 vf = *(const bf16x8*)&Vt[(n * 16 + lr) * ALD + ks * 32 + hi * 8];
                oacc[n] = mfma16(pa, vf, oacc[n]);
            }
        }
        __syncthreads();
    }

    const size_t orow0 = (size_t)(b * SEQ + qt * 64 + wave * 16);
#pragma unroll
    for (int n = 0; n < 4; ++n) {
#pragma unroll
        for (int j = 0; j < 4; ++j) {
            const int r = hi * 4 + j;
            const size_t idx = (orow0 + r) * DIM + h * 64 + n * 16 + lr;
            float val = oacc[n][j] / lrun[j];
            if (resid) val += resid[idx];
            outp[idx] = val;
        }
    }
}

extern "C" void kernel_launch(void* const* d_in, const int* in_sizes, int n_in,
                              void* d_out, int out_size, void* d_ws, size_t ws_size,
                              hipStream_t stream) {
    const float* x = (const float*)d_in[0];
    const float* text_emb = (const float*)d_in[1];
    const float* rotary = (const float*)d_in[3];
    const float* ln1_g = (const float*)d_in[4];
    const float* ln1_b = (const float*)d_in[5];
    const float* ln2_g = (const float*)d_in[6];
    const float* ln2_b = (const float*)d_in[7];
    const float* ln3_g = (const float*)d_in[8];
    const float* ln3_b = (const float*)d_in[9];
    const float* attn_in_w = (const float*)d_in[10];
    const float* attn_in_b = (const float*)d_in[11];
    const float* ca_in_w = (const float*)d_in[12];
    const float* ca_in_b = (const float*)d_in[13];
    const float* ca_out_w = (const float*)d_in[14];
    const float* ca_out_b = (const float*)d_in[15];
    const float* fc1_w = (const float*)d_in[16];
    const float* fc1_b = (const float*)d_in[17];
    const float* gate_w = (const float*)d_in[18];
    const float* gate_b = (const float*)d_in[19];
    const float* fc2_w = (const float*)d_in[20];
    const float* fc2_b = (const float*)d_in[21];

    char* ws = (char*)d_ws;
    float* xn = (float*)ws;                                   // 16 MiB f32
    bf16_t* qkv = (bf16_t*)(ws + 16777216);                   // 24 MiB bf16 (4096x3072)
    bf16_t* cq = qkv;                                         // 4096x1024 bf16
    bf16_t* ckv = (bf16_t*)(ws + 16777216 + 8388608);         // 1024x2048 bf16
    float* xA = (float*)(ws + 41943040);                      // 16 MiB f32
    float* ca_attn = (float*)(ws + 58720256);                 // 16 MiB f32 (dead after G4)
    bf16_t* hbuf = (bf16_t*)(ws + 58720256);                  // 32 MiB bf16 (4096x4096)
    float* out = (float*)d_out;

    // ---- self-attention branch ----
    ln_kernel<<<4096, 256, 0, stream>>>(x, ln1_g, ln1_b, xn);
    gemm_kernel<false, EPI_BF16><<<dim3(24, 32), 256, 0, stream>>>(
        xn, 1024, attn_in_w, 1024, attn_in_b, nullptr, qkv, 3072, 1024);
    rope_kernel<<<8192, 256, 0, stream>>>(qkv, rotary);
    attn_kernel<<<dim3(16, 16, 4), 256, 0, stream>>>(
        qkv, 3072, 0, qkv, 3072, 1024, qkv, 3072, 2048, 1024, x, xA, 0.125f);

    // ---- cross-attention branch ----
    ln_kernel<<<4096, 256, 0, stream>>>(xA, ln2_g, ln2_b, xn);
    gemm_kernel<false, EPI_BF16><<<dim3(8, 32), 256, 0, stream>>>(
        xn, 1024, ca_in_w, 1024, ca_in_b, nullptr, cq, 1024, 1024);
    gemm_kernel<false, EPI_BF16><<<dim3(16, 8), 256, 0, stream>>>(
        text_emb, 1024, ca_in_w + (size_t)1024 * 1024, 1024, ca_in_b + 1024, nullptr,
        ckv, 2048, 1024);
    attn_kernel<<<dim3(16, 16, 4), 256, 0, stream>>>(
        cq, 1024, 0, ckv, 2048, 0, ckv, 2048, 1024, 256, nullptr, ca_attn, 0.125f);
    gemm_kernel<false, EPI_F32_RESID><<<dim3(8, 32), 256, 0, stream>>>(
        ca_attn, 1024, ca_out_w, 1024, ca_out_b, xA, xA, 1024, 1024);

    // ---- MLP branch ----
    ln_kernel<<<4096, 256, 0, stream>>>(xA, ln3_g, ln3_b, xn);
    gemm_kernel<false, EPI_BF16_GELU><<<dim3(32, 32), 256, 0, stream>>>(
        xn, 1024, fc1_w, 1024, fc1_b, nullptr, hbuf, 4096, 1024);
    gemm_kernel<false, EPI_BF16_SIGMUL><<<dim3(32, 32), 256, 0, stream>>>(
        xn, 1024, gate_w, 1024, gate_b, hbuf, hbuf, 4096, 1024);
    gemm_kernel<true, EPI_F32_RESID><<<dim3(8, 32), 256, 0, stream>>>(
        hbuf, 4096, fc2_w, 4096, fc2_b, xA, out, 1024, 4096);
}

// Round 3
// 533.885 us; speedup vs baseline: 1.2363x; 1.2363x over previous
//
#include <hip/hip_runtime.h>
#include <hip/hip_bf16.h>

#define SEQ 1024
#define DIM 1024
#define NH 16

typedef __bf16 bf16_t;
typedef __bf16 bf16x8 __attribute__((ext_vector_type(8)));
typedef __bf16 bf16x4 __attribute__((ext_vector_type(4)));
typedef float f32x4 __attribute__((ext_vector_type(4)));

__device__ __forceinline__ f32x4 mfma16(bf16x8 a, bf16x8 b, f32x4 c) {
    return __builtin_amdgcn_mfma_f32_16x16x32_bf16(a, b, c, 0, 0, 0);
}

__device__ __forceinline__ void gload16(const bf16_t* g, bf16_t* l) {
    __builtin_amdgcn_global_load_lds(
        (const __attribute__((address_space(1))) void*)g,
        (__attribute__((address_space(3))) void*)l, 16, 0, 0);
}

// ---------------- f32 -> bf16 conversion (weights, text_emb) ----------------
__global__ __launch_bounds__(256) void cvt_kernel(const float* __restrict__ in,
                                                  bf16_t* __restrict__ out) {
    const int i = blockIdx.x * 256 + threadIdx.x;
    const float4 v = ((const float4*)in)[i];
    bf16x4 o = {(bf16_t)v.x, (bf16_t)v.y, (bf16_t)v.z, (bf16_t)v.w};
    ((bf16x4*)out)[i] = o;
}

// ---------------- LayerNorm: one block per row of 1024, bf16 out ----------------
__global__ __launch_bounds__(256) void ln_kernel(const float* __restrict__ in,
                                                 const float* __restrict__ g,
                                                 const float* __restrict__ bsh,
                                                 bf16_t* __restrict__ out) {
    __shared__ float red[4], red2[4];
    const int row = blockIdx.x, tid = threadIdx.x;
    const float4 v = ((const float4*)(in + (size_t)row * DIM))[tid];
    float s = v.x + v.y + v.z + v.w;
#pragma unroll
    for (int o = 32; o; o >>= 1) s += __shfl_down(s, o, 64);
    if ((tid & 63) == 0) red[tid >> 6] = s;
    __syncthreads();
    const float mean = (red[0] + red[1] + red[2] + red[3]) * (1.0f / DIM);
    const float dx = v.x - mean, dy = v.y - mean, dz = v.z - mean, dw = v.w - mean;
    float s2 = dx * dx + dy * dy + dz * dz + dw * dw;
#pragma unroll
    for (int o = 32; o; o >>= 1) s2 += __shfl_xor(s2, o, 64);
    if ((tid & 63) == 0) red2[tid >> 6] = s2;
    __syncthreads();
    const float var = (red2[0] + red2[1] + red2[2] + red2[3]) * (1.0f / DIM);
    const float rs = rsqrtf(var + 1e-5f);
    const float4 gv = ((const float4*)g)[tid];
    const float4 bv = ((const float4*)bsh)[tid];
    bf16x4 o4 = {(bf16_t)(dx * rs * gv.x + bv.x), (bf16_t)(dy * rs * gv.y + bv.y),
                 (bf16_t)(dz * rs * gv.z + bv.z), (bf16_t)(dw * rs * gv.w + bv.w)};
    ((bf16x4*)(out + (size_t)row * DIM))[tid] = o4;
}

// ---------------- RoPE in-place on q,k sections of qkv (bf16) ----------------
__global__ __launch_bounds__(256) void rope_kernel(bf16_t* __restrict__ qkv,
                                                   const float* __restrict__ rp) {
    const int t = blockIdx.x * 256 + threadIdx.x;  // 4096*512 threads
    const int row = t >> 9;
    const int rem = t & 511;
    const int h = rem >> 5, d = rem & 31;
    const int s = row & (SEQ - 1);
    const float p0 = rp[s * 64 + d];
    const float p1 = rp[s * 64 + d + 32];
    float s0, c0, s1, c1;
    sincosf(p0, &s0, &c0);
    sincosf(p1, &s1, &c1);
    const size_t base = (size_t)row * 3072 + h * 64 + d;
#pragma unroll
    for (int off = 0; off <= 1024; off += 1024) {
        const float a = (float)qkv[base + off];
        const float b = (float)qkv[base + off + 32];
        qkv[base + off] = (bf16_t)(a * c0 - b * s0);
        qkv[base + off + 32] = (bf16_t)(b * c1 + a * s1);
    }
}

// ---------------- bf16 MFMA GEMM (m97 structure): C = epi(A @ W^T + bias) ----
// A: M x K bf16 row-major (lda); W: N x K bf16 row-major (ldw).
// 256 thr = 4 waves (2x2), tile 128x128, BK=32, global_load_lds staging.
enum { EPI_BF16 = 0, EPI_F32_RESID = 1, EPI_BF16_GELU = 2, EPI_BF16_SIGMUL = 3 };

template <int EPI>
__global__ __launch_bounds__(256) void gemm_bf16(
    const bf16_t* __restrict__ A, int lda, const bf16_t* __restrict__ W, int ldw,
    const float* __restrict__ bias, const void* __restrict__ aux,
    void* __restrict__ outv, int ldo, int K) {
    __shared__ bf16_t As[128 * 32];
    __shared__ bf16_t Bs[128 * 32];
    const int tid = threadIdx.x;
    const int wave = tid >> 6, lane = tid & 63;
    const int wr = wave >> 1, wc = wave & 1;
    const int lr = lane & 15, hi = lane >> 4;

    // XCD-aware swizzle (all grids have nwg % 8 == 0)
    const int gy = gridDim.y;
    int lin = blockIdx.x * gy + blockIdx.y;
    const int cpx = (gridDim.x * gy) >> 3;
    lin = (lin & 7) * cpx + (lin >> 3);
    const int rowB0 = (lin / gy) * 128;  // N tile
    const int rowA0 = (lin % gy) * 128;  // M tile

    // staging decomposition: chunk ci (0..7) covers rows ci*16..+15, lane l ->
    // row ci*16 + (l>>2), col (l&3)*8 ; LDS linear at elem ci*512 + l*8
    const int sr = lane >> 2, sc = (lane & 3) * 8;

    f32x4 acc[4][4];
#pragma unroll
    for (int m = 0; m < 4; ++m)
#pragma unroll
        for (int n = 0; n < 4; ++n) acc[m][n] = (f32x4){0.f, 0.f, 0.f, 0.f};

    for (int k0 = 0; k0 < K; k0 += 32) {
        const bf16_t* Ag = A + (size_t)(rowA0) * lda + k0;
        const bf16_t* Bg = W + (size_t)(rowB0) * ldw + k0;
#pragma unroll
        for (int t = 0; t < 2; ++t) {
            const int ci = wave * 2 + t;
            gload16(Ag + (size_t)(ci * 16 + sr) * lda + sc, As + ci * 512);
            gload16(Bg + (size_t)(ci * 16 + sr) * ldw + sc, Bs + ci * 512);
        }
        __syncthreads();
        bf16x8 af[4], bfr[4];
#pragma unroll
        for (int m = 0; m < 4; ++m)
            af[m] = *(const bf16x8*)&As[(wr * 64 + m * 16 + lr) * 32 + hi * 8];
#pragma unroll
        for (int n = 0; n < 4; ++n)
            bfr[n] = *(const bf16x8*)&Bs[(wc * 64 + n * 16 + lr) * 32 + hi * 8];
#pragma unroll
        for (int m = 0; m < 4; ++m)
#pragma unroll
            for (int n = 0; n < 4; ++n) acc[m][n] = mfma16(af[m], bfr[n], acc[m][n]);
        __syncthreads();
    }

    float bn[4];
#pragma unroll
    for (int n = 0; n < 4; ++n) bn[n] = bias[rowB0 + wc * 64 + n * 16 + lr];
#pragma unroll
    for (int m = 0; m < 4; ++m) {
#pragma unroll
        for (int j = 0; j < 4; ++j) {
            const int row = rowA0 + wr * 64 + m * 16 + hi * 4 + j;
#pragma unroll
            for (int n = 0; n < 4; ++n) {
                const int col = rowB0 + wc * 64 + n * 16 + lr;
                float val = acc[m][n][j] + bn[n];
                const size_t oidx = (size_t)row * ldo + col;
                if constexpr (EPI == EPI_BF16) {
                    ((bf16_t*)outv)[oidx] = (bf16_t)val;
                } else if constexpr (EPI == EPI_F32_RESID) {
                    ((float*)outv)[oidx] = val + ((const float*)aux)[oidx];
                } else if constexpr (EPI == EPI_BF16_GELU) {
                    ((bf16_t*)outv)[oidx] =
                        (bf16_t)(0.5f * val * (1.0f + erff(val * 0.70710678118f)));
                } else {  // EPI_BF16_SIGMUL
                    const float sg = 1.0f / (1.0f + expf(-val));
                    ((bf16_t*)outv)[oidx] =
                        (bf16_t)(sg * (float)((const bf16_t*)aux)[oidx]);
                }
            }
        }
    }
}

// ---------------- flash attention (non-causal), 4 waves, 64 q-rows/block ----
#define ALD 72
template <bool OUTBF>
__global__ __launch_bounds__(256) void attn_kernel(
    const bf16_t* __restrict__ qp, int ldq, int qoff,
    const bf16_t* __restrict__ kp, int ldk, int koff,
    const bf16_t* __restrict__ vp, int ldv, int voff, int skv,
    const float* __restrict__ resid, void* __restrict__ outp, float scale) {
    __shared__ bf16_t Ks[64 * ALD];
    __shared__ bf16_t Vt[64 * ALD];
    __shared__ bf16_t Ps[4 * 16 * ALD];
    const int b = blockIdx.z, h = blockIdx.y, qt = blockIdx.x;
    const int tid = threadIdx.x;
    const int wave = tid >> 6, lane = tid & 63;
    const int lr = lane & 15, hi = lane >> 4;

    const size_t qrow = (size_t)(b * SEQ + qt * 64 + wave * 16 + lr);
    const bf16_t* qb = qp + qrow * ldq + qoff + h * 64;
    const bf16x8 qf0 = *(const bf16x8*)(qb + hi * 8);
    const bf16x8 qf1 = *(const bf16x8*)(qb + 32 + hi * 8);

    f32x4 oacc[4];
#pragma unroll
    for (int n = 0; n < 4; ++n) oacc[n] = (f32x4){0.f, 0.f, 0.f, 0.f};
    float mrun[4] = {-1e30f, -1e30f, -1e30f, -1e30f};
    float lrun[4] = {0.f, 0.f, 0.f, 0.f};

    bf16_t* pw = &Ps[wave * 16 * ALD];
    const int nkt = skv >> 6;
    for (int kt = 0; kt < nkt; ++kt) {
#pragma unroll
        for (int t = 0; t < 2; ++t) {
            const int idx = t * 256 + tid;  // 0..511
            const int key = idx >> 3, c8 = (idx & 7) * 8;
            const size_t krow = (size_t)(b * skv + kt * 64 + key);
            bf16x8 kv = *(const bf16x8*)(kp + krow * ldk + koff + h * 64 + c8);
            *(bf16x8*)&Ks[key * ALD + c8] = kv;
            bf16x8 vv = *(const bf16x8*)(vp + krow * ldv + voff + h * 64 + c8);
#pragma unroll
            for (int i = 0; i < 8; ++i) Vt[(c8 + i) * ALD + key] = vv[i];
        }
        __syncthreads();

        f32x4 s[4];
#pragma unroll
        for (int n = 0; n < 4; ++n) {
            f32x4 z = (f32x4){0.f, 0.f, 0.f, 0.f};
            z = mfma16(qf0, *(const bf16x8*)&Ks[(n * 16 + lr) * ALD + hi * 8], z);
            z = mfma16(qf1, *(const bf16x8*)&Ks[(n * 16 + lr) * ALD + 32 + hi * 8], z);
            s[n] = z * scale;
        }
        float alpha[4];
#pragma unroll
        for (int j = 0; j < 4; ++j) {
            float mt = fmaxf(fmaxf(s[0][j], s[1][j]), fmaxf(s[2][j], s[3][j]));
#pragma unroll
            for (int o = 8; o >= 1; o >>= 1) mt = fmaxf(mt, __shfl_xor(mt, o, 64));
            const float mnew = fmaxf(mrun[j], mt);
            alpha[j] = expf(mrun[j] - mnew);
            float rsum = 0.f;
#pragma unroll
            for (int n = 0; n < 4; ++n) {
                const float p = expf(s[n][j] - mnew);
                s[n][j] = p;
                rsum += p;
            }
#pragma unroll
            for (int o = 8; o >= 1; o >>= 1) rsum += __shfl_xor(rsum, o, 64);
            lrun[j] = lrun[j] * alpha[j] + rsum;
            mrun[j] = mnew;
        }
#pragma unroll
        for (int j = 0; j < 4; ++j) {
            const int pr = hi * 4 + j;
#pragma unroll
            for (int n = 0; n < 4; ++n) pw[pr * ALD + n * 16 + lr] = (bf16_t)s[n][j];
        }
#pragma unroll
        for (int n = 0; n < 4; ++n)
#pragma unroll
            for (int j = 0; j < 4; ++j) oacc[n][j] *= alpha[j];
#pragma unroll
        for (int ks = 0; ks < 2; ++ks) {
            const bf16x8 pa = *(const bf16x8*)&pw[lr * ALD + ks * 32 + hi * 8];
#pragma unroll
            for (int n = 0; n < 4; ++n) {
                const bf16x8 vf = *(const bf16x8*)&Vt[(n * 16 + lr) * ALD + ks * 32 + hi * 8];
                oacc[n] = mfma16(pa, vf, oacc[n]);
            }
        }
        __syncthreads();
    }

    const size_t orow0 = (size_t)(b * SEQ + qt * 64 + wave * 16);
#pragma unroll
    for (int n = 0; n < 4; ++n) {
#pragma unroll
        for (int j = 0; j < 4; ++j) {
            const int r = hi * 4 + j;
            const size_t idx = (orow0 + r) * DIM + h * 64 + n * 16 + lr;
            float val = oacc[n][j] / lrun[j];
            if constexpr (OUTBF) {
                ((bf16_t*)outp)[idx] = (bf16_t)val;
            } else {
                ((float*)outp)[idx] = val + resid[idx];
            }
        }
    }
}

extern "C" void kernel_launch(void* const* d_in, const int* in_sizes, int n_in,
                              void* d_out, int out_size, void* d_ws, size_t ws_size,
                              hipStream_t stream) {
    const float* x = (const float*)d_in[0];
    const float* text_emb = (const float*)d_in[1];
    const float* rotary = (const float*)d_in[3];
    const float* ln1_g = (const float*)d_in[4];
    const float* ln1_b = (const float*)d_in[5];
    const float* ln2_g = (const float*)d_in[6];
    const float* ln2_b = (const float*)d_in[7];
    const float* ln3_g = (const float*)d_in[8];
    const float* ln3_b = (const float*)d_in[9];
    const float* attn_in_w = (const float*)d_in[10];
    const float* attn_in_b = (const float*)d_in[11];
    const float* ca_in_w = (const float*)d_in[12];
    const float* ca_in_b = (const float*)d_in[13];
    const float* ca_out_w = (const float*)d_in[14];
    const float* ca_out_b = (const float*)d_in[15];
    const float* fc1_w = (const float*)d_in[16];
    const float* fc1_b = (const float*)d_in[17];
    const float* gate_w = (const float*)d_in[18];
    const float* gate_b = (const float*)d_in[19];
    const float* fc2_w = (const float*)d_in[20];
    const float* fc2_b = (const float*)d_in[21];

    char* ws = (char*)d_ws;
    // bf16 weight region (persistent through call): 40 MiB
    bf16_t* attn_w_bf = (bf16_t*)(ws);
    bf16_t* ca_in_bf = (bf16_t*)(ws + 6291456);
    bf16_t* ca_out_bf = (bf16_t*)(ws + 12582912);
    bf16_t* fc1_bf = (bf16_t*)(ws + 14680064);
    bf16_t* gate_bf = (bf16_t*)(ws + 23068672);
    bf16_t* fc2_bf = (bf16_t*)(ws + 31457280);
    bf16_t* text_bf = (bf16_t*)(ws + 39845888);
    bf16_t* xn = (bf16_t*)(ws + 41943040);      // 8 MiB
    float* xA = (float*)(ws + 50331648);        // 16 MiB (residual stream)
    char* S = ws + 67108864;                    // 32 MiB scratch
    bf16_t* qkv = (bf16_t*)S;                   // 24 MiB (self-attn)
    bf16_t* cq = (bf16_t*)S;                    // 8 MiB
    bf16_t* ckv = (bf16_t*)(S + 8388608);       // 4 MiB
    bf16_t* ca_attn = (bf16_t*)(S + 12582912);  // 8 MiB
    bf16_t* hbuf = (bf16_t*)S;                  // 32 MiB (MLP)
    float* out = (float*)d_out;

    // ---- weight / text conversion to bf16 ----
    cvt_kernel<<<3072, 256, 0, stream>>>(attn_in_w, attn_w_bf);
    cvt_kernel<<<3072, 256, 0, stream>>>(ca_in_w, ca_in_bf);
    cvt_kernel<<<1024, 256, 0, stream>>>(ca_out_w, ca_out_bf);
    cvt_kernel<<<4096, 256, 0, stream>>>(fc1_w, fc1_bf);
    cvt_kernel<<<4096, 256, 0, stream>>>(gate_w, gate_bf);
    cvt_kernel<<<4096, 256, 0, stream>>>(fc2_w, fc2_bf);
    cvt_kernel<<<1024, 256, 0, stream>>>(text_emb, text_bf);

    // ---- self-attention branch ----
    ln_kernel<<<4096, 256, 0, stream>>>(x, ln1_g, ln1_b, xn);
    gemm_bf16<EPI_BF16><<<dim3(24, 32), 256, 0, stream>>>(
        xn, 1024, attn_w_bf, 1024, attn_in_b, nullptr, qkv, 3072, 1024);
    rope_kernel<<<8192, 256, 0, stream>>>(qkv, rotary);
    attn_kernel<false><<<dim3(16, 16, 4), 256, 0, stream>>>(
        qkv, 3072, 0, qkv, 3072, 1024, qkv, 3072, 2048, 1024, x, xA, 0.125f);

    // ---- cross-attention branch ----
    ln_kernel<<<4096, 256, 0, stream>>>(xA, ln2_g, ln2_b, xn);
    gemm_bf16<EPI_BF16><<<dim3(8, 32), 256, 0, stream>>>(
        xn, 1024, ca_in_bf, 1024, ca_in_b, nullptr, cq, 1024, 1024);
    gemm_bf16<EPI_BF16><<<dim3(16, 8), 256, 0, stream>>>(
        text_bf, 1024, ca_in_bf + (size_t)1024 * 1024, 1024, ca_in_b + 1024, nullptr,
        ckv, 2048, 1024);
    attn_kernel<true><<<dim3(16, 16, 4), 256, 0, stream>>>(
        cq, 1024, 0, ckv, 2048, 0, ckv, 2048, 1024, 256, nullptr, ca_attn, 0.125f);
    gemm_bf16<EPI_F32_RESID><<<dim3(8, 32), 256, 0, stream>>>(
        ca_attn, 1024, ca_out_bf, 1024, ca_out_b, xA, xA, 1024, 1024);

    // ---- MLP branch ----
    ln_kernel<<<4096, 256, 0, stream>>>(xA, ln3_g, ln3_b, xn);
    gemm_bf16<EPI_BF16_GELU><<<dim3(32, 32), 256, 0, stream>>>(
        xn, 1024, fc1_bf, 1024, fc1_b, nullptr, hbuf, 4096, 1024);
    gemm_bf16<EPI_BF16_SIGMUL><<<dim3(32, 32), 256, 0, stream>>>(
        xn, 1024, gate_bf, 1024, gate_b, hbuf, hbuf, 4096, 1024);
    gemm_bf16<EPI_F32_RESID><<<dim3(8, 32), 256, 0, stream>>>(
        hbuf, 4096, fc2_bf, 4096, fc2_b, xA, out, 1024, 4096);
}